// Round 14
// baseline (285.530 us; speedup 1.0000x reference)
//
#include <hip/hip_runtime.h>
#include <hip/hip_bf16.h>
#include <stdint.h>

#define N_NODES 100000
#define DIM 128
#define NREL 4
#define NEDGE 500000
#define M_FLAT (NREL * N_NODES)        // 400000 flat (r,node) slots
#define TOT_E (NREL * NEDGE)           // 2M edges
#define BSLOT 1024                     // flat slots per bucket
#define NBK ((M_FLAT + BSLOT - 1) / BSLOT)   // 391 buckets
#define CAP 8192                       // padded edge capacity per bucket (mean 5120, 43 sigma slack)
#define CHUNK 4096                     // edges per bscatter role-block (31.4KB LDS -> 5 blocks/CU)
#define NBSC ((TOT_E + CHUNK - 1) / CHUNK)            // 489 bscatter blocks
#define NQ (N_NODES * DIM / 4)                        // 3.2M float4 elements for xb
#define XB_BATCH 8
#define NBXB ((NQ + 256 * XB_BATCH - 1) / (256 * XB_BATCH))   // 1563 xb blocks
#define NBPREP ((5 * DIM * DIM + 255) / 256)          // 320 prep blocks

typedef __attribute__((ext_vector_type(8))) short short8;
typedef __attribute__((ext_vector_type(4))) float f32x4;
typedef __attribute__((ext_vector_type(2))) float f32x2;

__device__ __forceinline__ unsigned short f2bf(float f) {
  unsigned int u = __float_as_uint(f);
  u += 0x7fffu + ((u >> 16) & 1u);   // RNE
  return (unsigned short)(u >> 16);
}

// Fused preprocessing, role-split by blockIdx. CHUNK=4096 keeps static LDS at
// ~31.4KB so ALL roles run 5 blocks/CU.
__global__ __launch_bounds__(256) void pre_kernel(
    const int* __restrict__ src, const int* __restrict__ dst,
    int* __restrict__ bcnt, unsigned int* __restrict__ gpairs,
    const float* __restrict__ x, unsigned short* __restrict__ xb,
    const float* __restrict__ Ws, const float* __restrict__ Wn,
    const float* __restrict__ bv, unsigned short* __restrict__ Wt,
    float* __restrict__ biasc) {
  __shared__ unsigned int buf[CHUNK];        // 16 KB
  __shared__ unsigned short barr[CHUNK];     // 8 KB
  __shared__ int hist[NBK];                  // 1.6 KB
  __shared__ int sbase[NBK];
  __shared__ int lcur[NBK];
  __shared__ int gbase[NBK];
  __shared__ int part[256];                  // 1 KB
  int bid = blockIdx.x;
  int tid = threadIdx.x;

  if (bid < NBSC) {
    // ---- bscatter role ----
    int base = bid * CHUNK;
    int m = TOT_E - base; if (m > CHUNK) m = CHUNK;
    for (int i = tid; i < NBK; i += 256) { hist[i] = 0; lcur[i] = 0; }
    __syncthreads();
    unsigned int pk[CHUNK / 256];
    int bk[CHUNK / 256];
#pragma unroll
    for (int k = 0; k < CHUNK / 256; ++k) {
      int i = k * 256 + tid;
      int idx = base + i;
      int b = -1; unsigned int p = 0;
      if (i < m) {
        int r = idx / NEDGE;
        int fl = r * N_NODES + dst[idx];
        b = fl >> 10;
        p = ((unsigned int)(fl & (BSLOT - 1)) << 17) | (unsigned int)src[idx];
        atomicAdd(&hist[b], 1);
      }
      pk[k] = p; bk[k] = b;
    }
    __syncthreads();
    // two-pass exclusive scan over hist[0..NBK) (NBK = 391 > 256)
    {
      int vA = hist[tid];
      part[tid] = vA;
      __syncthreads();
      for (int o = 1; o < 256; o <<= 1) {
        int u = (tid >= o) ? part[tid - o] : 0;
        __syncthreads();
        part[tid] += u;
        __syncthreads();
      }
      sbase[tid] = part[tid] - vA;
      int totalA = part[255];
      __syncthreads();
      int vB = (256 + tid < NBK) ? hist[256 + tid] : 0;
      part[tid] = vB;
      __syncthreads();
      for (int o = 1; o < 256; o <<= 1) {
        int u = (tid >= o) ? part[tid - o] : 0;
        __syncthreads();
        part[tid] += u;
        __syncthreads();
      }
      if (256 + tid < NBK) sbase[256 + tid] = totalA + part[tid] - vB;
    }
    __syncthreads();
#pragma unroll
    for (int k = 0; k < CHUNK / 256; ++k) {
      if (bk[k] >= 0) {
        int pos = sbase[bk[k]] + atomicAdd(&lcur[bk[k]], 1);
        buf[pos] = pk[k];
        barr[pos] = (unsigned short)bk[k];
      }
    }
    __syncthreads();
    for (int i = tid; i < NBK; i += 256)
      if (hist[i] > 0) gbase[i] = i * CAP + atomicAdd(&bcnt[i], hist[i]) - sbase[i];
    __syncthreads();
    for (int j = tid; j < m; j += 256)
      gpairs[gbase[barr[j]] + j] = buf[j];
  } else if (bid < NBSC + NBXB) {
    // ---- xb role ----
    int base = (bid - NBSC) * (256 * XB_BATCH);
    float4 v[XB_BATCH];
#pragma unroll
    for (int k = 0; k < XB_BATCH; ++k) {
      int i = base + k * 256 + tid;
      if (i < NQ) v[k] = ((const float4*)x)[i];
    }
#pragma unroll
    for (int k = 0; k < XB_BATCH; ++k) {
      int i = base + k * 256 + tid;
      if (i < NQ) {
        ushort4 s;
        s.x = f2bf(v[k].x); s.y = f2bf(v[k].y); s.z = f2bf(v[k].z); s.w = f2bf(v[k].w);
        ((ushort4*)xb)[i] = s;
      }
    }
  } else {
    // ---- prep role: combined B in MFMA fragment order ----
    int t3 = (bid - NBSC - NBXB) * 256 + tid;
    if (t3 < 5 * DIM * DIM) {
      int b = t3 / (DIM * DIM);
      int idx = t3 - b * DIM * DIM;   // k*DIM + n
      int k = idx >> 7, n = idx & 127;
      float v;
      if (b == 0)
        v = 0.25f * (Ws[idx] + Ws[DIM * DIM + idx] + Ws[2 * DIM * DIM + idx] + Ws[3 * DIM * DIM + idx]);
      else
        v = 0.25f * Wn[(b - 1) * DIM * DIM + idx];
      int ks = k >> 5, kq = (k >> 3) & 3, j = k & 7;
      int ct = n >> 4, lr = n & 15;
      int lane = kq * 16 + lr;
      Wt[((((b * 4 + ks) * 8) + ct) * 64 + lane) * 8 + j] = f2bf(v);
    }
    if (t3 < DIM)
      biasc[t3] = 0.25f * (bv[t3] + bv[DIM + t3] + bv[2 * DIM + t3] + bv[3 * DIM + t3]);
  }
}

// One 512-thread block per bucket. Pairs register-cached (gpairs read once),
// scan phases halved, lofs u16. LDS ~44KB -> 3 blocks/CU. ssrc staged via
// sbuf, written coalesced. offs bucket-strided: consumer idx = fl + (fl>>10).
__global__ __launch_bounds__(512) void bfill_kernel(
    const unsigned int* __restrict__ gpairs, const int* __restrict__ bcnt,
    int* __restrict__ offs, int* __restrict__ ssrc) {
  __shared__ int lcnt[BSLOT];              // 4 KB
  __shared__ unsigned short lofs[BSLOT];   // 2 KB
  __shared__ int lcur[BSLOT];              // 4 KB
  __shared__ int part[512];                // 2 KB
  __shared__ int sbuf[CAP];                // 32 KB
  int b = blockIdx.x;
  int tid = threadIdx.x;
  int base = b * CAP;
  int cntb = bcnt[b];
  int flBase = b << 10;
  int flCount = M_FLAT - flBase; if (flCount > BSLOT) flCount = BSLOT;
  for (int i = tid; i < BSLOT; i += 512) { lcnt[i] = 0; lcur[i] = 0; }
  __syncthreads();
  unsigned int pk[CAP / 512];
#pragma unroll
  for (int k = 0; k < CAP / 512; ++k) {
    int j = k * 512 + tid;
    pk[k] = (j < cntb) ? gpairs[base + j] : 0u;
  }
#pragma unroll
  for (int k = 0; k < CAP / 512; ++k) {
    int j = k * 512 + tid;
    if (j < cntb) atomicAdd(&lcnt[pk[k] >> 17], 1);
  }
  __syncthreads();
  int vals[2]; int s0 = 0;
#pragma unroll
  for (int k = 0; k < 2; ++k) { vals[k] = lcnt[tid * 2 + k]; s0 += vals[k]; }
  part[tid] = s0;
  __syncthreads();
  for (int o = 1; o < 512; o <<= 1) {
    int u = (tid >= o) ? part[tid - o] : 0;
    __syncthreads();
    part[tid] += u;
    __syncthreads();
  }
  int excl = part[tid] - s0;
  lofs[tid * 2] = (unsigned short)excl;
  lofs[tid * 2 + 1] = (unsigned short)(excl + vals[0]);
  __syncthreads();
  for (int i = tid; i <= flCount; i += 512)
    offs[b * (BSLOT + 1) + i] = base + ((i < BSLOT) ? (int)lofs[i] : cntb);
#pragma unroll
  for (int k = 0; k < CAP / 512; ++k) {
    int j = k * 512 + tid;
    if (j < cntb) {
      int li = pk[k] >> 17;
      int pos = atomicAdd(&lcur[li], 1);
      sbuf[(int)lofs[li] + pos] = (int)(pk[k] & 0x1FFFFu);
    }
  }
  __syncthreads();
  for (int j = tid; j < cntb; j += 512)
    ssrc[base + j] = sbuf[j];
}

// One wave per node, ALL 4 relations interleaved (fabric-bound at ~4.2 TB/s on
// the random 256B gather — six consecutive identical profiles; kept as-is).
__global__ __launch_bounds__(256) void aggregate_kernel(
    const unsigned int* __restrict__ xb32, const int* __restrict__ ssrc,
    const int* __restrict__ offs, unsigned int* __restrict__ agg32) {
  int lane = threadIdx.x & 63;
  int n = blockIdx.x * 4 + (int)__builtin_amdgcn_readfirstlane(threadIdx.x >> 6);
  if (n >= N_NODES) return;

  int start[NREL], end[NREL];
#pragma unroll
  for (int r = 0; r < NREL; ++r) {
    int fl = r * N_NODES + n;
    int oidx = fl + (fl >> 10);   // bucket-strided offs index
    start[r] = __builtin_amdgcn_readfirstlane(offs[oidx]);
    end[r] = __builtin_amdgcn_readfirstlane(offs[oidx + 1]);
  }

  unsigned int v[NREL][8];
#pragma unroll
  for (int r = 0; r < NREL; ++r) {
    int s = start[r], m = end[r] - s;
#pragma unroll
    for (int k = 0; k < 8; ++k) {
      int ea = (m > 0) ? (s + ((k < m) ? k : (m - 1))) : 0;  // c==0: safe slot 0
      int idx = ssrc[ea];                                    // uniform index
      v[r][k] = xb32[((unsigned)idx << 6) | (unsigned)lane]; // sgpr-base + voffset
    }
  }

  f32x2 acc[NREL];
#pragma unroll
  for (int r = 0; r < NREL; ++r) {
    f32x2 a = {0.f, 0.f};
    int m = end[r] - start[r];
#pragma unroll
    for (int k = 0; k < 8; ++k) {
      unsigned int u = (k < m) ? v[r][k] : 0u;
      f32x2 d;
      d.x = __uint_as_float(u << 16);          // low bf16
      d.y = __uint_as_float(u & 0xffff0000u);  // high bf16
      a += d;                                   // v_pk_add_f32
    }
    acc[r] = a;
  }

  bool anyTail = ((end[0] - start[0]) > 8) | ((end[1] - start[1]) > 8) |
                 ((end[2] - start[2]) > 8) | ((end[3] - start[3]) > 8);
  if (anyTail) {
#pragma unroll
    for (int r = 0; r < NREL; ++r) {
      for (int e = start[r] + 8; e < end[r]; e += 8) {
        int m = end[r] - e;   // > 0, wave-uniform
        unsigned int w[8];
#pragma unroll
        for (int k = 0; k < 8; ++k) {
          int idx = ssrc[e + ((k < m) ? k : 0)];
          w[k] = xb32[((unsigned)idx << 6) | (unsigned)lane];
        }
#pragma unroll
        for (int k = 0; k < 8; ++k) {
          unsigned int u = (k < m) ? w[k] : 0u;
          f32x2 d;
          d.x = __uint_as_float(u << 16);
          d.y = __uint_as_float(u & 0xffff0000u);
          acc[r] += d;
        }
      }
    }
  }

#pragma unroll
  for (int r = 0; r < NREL; ++r) {
    int c = end[r] - start[r];
    float inv = __builtin_amdgcn_rcpf((float)(c > 0 ? c : 1));
    float lo = acc[r].x * inv, hi = acc[r].y * inv;
    unsigned int packed;
    asm("v_cvt_pk_bf16_f32 %0, %1, %2" : "=v"(packed) : "v"(lo), "v"(hi));
    agg32[((size_t)r * N_NODES + n) * 64 + lane] = packed;
  }
}

// 64-row-block GEMM with DOUBLE-BUFFERED B (64 KB LDS): slab bi+1 stages into
// the idle buffer DURING slab bi's MFMAs -> one barrier per slab (was 2) and
// the ~300-400cy L2 restage latency hides under MFMA issue. A-fragments
// register-direct from global, one slab ahead. 2 blocks/CU (8 waves) —
// trades TLP for ILP vs the 5-block single-buffer version (R14 A/B).
__global__ __launch_bounds__(256) void gemm_kernel(
    const unsigned short* __restrict__ xb, const unsigned short* __restrict__ Wt,
    const float* __restrict__ biasc, float* __restrict__ out,
    const unsigned short* __restrict__ agg) {
  __shared__ short8 Bs[2][2048];   // 64 KB: two B slabs
  int tid = threadIdx.x;
  int lane = tid & 63;
  int wv = __builtin_amdgcn_readfirstlane(tid >> 6);
  int bandRow = blockIdx.x * 64 + wv * 16;
  int valid = bandRow < N_NODES;           // wave-uniform (N_NODES % 16 == 0)
  int ldRow = valid ? bandRow : 0;
  int quad = lane >> 4;
  int lr = lane & 15;
  const short8* Bp = (const short8*)Wt;

  float bias8[8];
#pragma unroll
  for (int ct = 0; ct < 8; ++ct) bias8[ct] = biasc[ct * 16 + lr];

  f32x4 zero = {0.f, 0.f, 0.f, 0.f};
  f32x4 acc[8];
#pragma unroll
  for (int ct = 0; ct < 8; ++ct) acc[ct] = zero;

  // stage B slab 0 into Bs[0] and preload A slab 0 (xb) before the barrier
#pragma unroll
  for (int p = 0; p < 8; ++p) Bs[0][p * 256 + tid] = Bp[p * 256 + tid];
  short8 ac[4];
  {
    const unsigned short* rowp = xb + (size_t)(ldRow + lr) * DIM;
#pragma unroll
    for (int ks = 0; ks < 4; ++ks)
      ac[ks] = *(const short8*)(rowp + ks * 32 + quad * 8);
  }
  __syncthreads();

#pragma unroll
  for (int bi = 0; bi < 5; ++bi) {
    const int cur = bi & 1;
    short8 an[4];
    if (bi < 4) {
      // prefetch next A (HBM, longest latency — issue first)
      const unsigned short* rowp = agg + (size_t)bi * N_NODES * DIM + (size_t)(ldRow + lr) * DIM;
#pragma unroll
      for (int ks = 0; ks < 4; ++ks)
        an[ks] = *(const short8*)(rowp + ks * 32 + quad * 8);
      // stage next B into the idle buffer (L2-hot; overlaps MFMAs below)
#pragma unroll
      for (int p = 0; p < 8; ++p)
        Bs[cur ^ 1][p * 256 + tid] = Bp[(size_t)(bi + 1) * 2048 + p * 256 + tid];
    }
#pragma unroll
    for (int ks = 0; ks < 4; ++ks) {
#pragma unroll
      for (int ct = 0; ct < 8; ++ct) {
        short8 bf = Bs[cur][(ks * 8 + ct) * 64 + lane];
        acc[ct] = __builtin_amdgcn_mfma_f32_16x16x32_bf16(ac[ks], bf, acc[ct], 0, 0, 0);
      }
    }
    __syncthreads();   // stage(bi+1) complete + all reads of Bs[cur] done
#pragma unroll
    for (int ks = 0; ks < 4; ++ks) ac[ks] = an[ks];
  }

  if (valid) {
#pragma unroll
    for (int i = 0; i < 4; ++i) {
      int g = bandRow + quad * 4 + i;
#pragma unroll
      for (int ct = 0; ct < 8; ++ct)
        out[(size_t)g * DIM + ct * 16 + lr] = acc[ct][i] + bias8[ct];
    }
  }
}

extern "C" void kernel_launch(void* const* d_in, const int* in_sizes, int n_in,
                              void* d_out, int out_size, void* d_ws, size_t ws_size,
                              hipStream_t stream) {
  const float* x = (const float*)d_in[0];
  const int* src = (const int*)d_in[1];
  const int* dst = (const int*)d_in[2];
  const float* Wself = (const float*)d_in[3];
  const float* Wneigh = (const float*)d_in[4];
  const float* bv = (const float*)d_in[5];
  float* out = (float*)d_out;

  char* ws = (char*)d_ws;
  size_t off = 0;
  int* bcnt = (int*)(ws + off);        off += 2048;                                    // 391 cursors
  unsigned short* Wt = (unsigned short*)(ws + off);  off += 5 * DIM * DIM * 2;         // 160 KB
  float* biasc = (float*)(ws + off);   off += DIM * 4;
  int* offs = (int*)(ws + off);        off += ((size_t)NBK * (BSLOT + 1) * 4 + 15) & ~15;  // 1.6 MB
  unsigned short* xb = (unsigned short*)(ws + off);  off += (size_t)N_NODES * DIM * 2;  // 25.6 MB
  unsigned int* gpairs = (unsigned int*)(ws + off);  off += (size_t)NBK * CAP * 4;      // 12.8 MB
  int* ssrc = (int*)(ws + off);        off += (size_t)NBK * CAP * 4;                    // 12.8 MB
  unsigned short* agg = (unsigned short*)(ws + off);  // 4 slabs = 102.4 MB

  hipMemsetAsync(bcnt, 0, 2048, stream);
  pre_kernel<<<NBSC + NBXB + NBPREP, 256, 0, stream>>>(src, dst, bcnt, gpairs,
                                                       x, xb, Wself, Wneigh, bv, Wt, biasc);
  bfill_kernel<<<NBK, 512, 0, stream>>>(gpairs, bcnt, offs, ssrc);
  aggregate_kernel<<<(N_NODES + 3) / 4, 256, 0, stream>>>((const unsigned int*)xb, ssrc,
                                                          offs, (unsigned int*)agg);
  gemm_kernel<<<(N_NODES + 63) / 64, 256, 0, stream>>>(xb, Wt, biasc, out, agg);
}